// Round 1
// baseline (112.938 us; speedup 1.0000x reference)
//
#include <hip/hip_runtime.h>
#include <hip/hip_bf16.h>

typedef __attribute__((ext_vector_type(8))) short s8v;     // 8 bf16 operand
typedef __attribute__((ext_vector_type(4))) float f4v;     // fp32 accum

__device__ inline ushort f2bf(float f) {
    unsigned u = __builtin_bit_cast(unsigned, f);
    unsigned r = (u + 0x7fffu + ((u >> 16) & 1u)) >> 16;   // RTNE
    return (ushort)r;
}

__device__ inline void gload16(const ushort* g, ushort* l) {
    __builtin_amdgcn_global_load_lds(
        (const __attribute__((address_space(1))) unsigned*)g,
        (__attribute__((address_space(3))) unsigned*)l, 16, 0, 0);
}

// ---------------- x: [B][C][L] fp32 -> xb16 [B][C][L] bf16 (straight) + xlc [B][L][C] bf16 (transposed)
__global__ __launch_bounds__(256) void xprep(const float* __restrict__ x,
                                             ushort* __restrict__ xb,
                                             ushort* __restrict__ xlc) {
    __shared__ __align__(16) ushort t[64][72];
    int lt = blockIdx.x, ct = blockIdx.y, b = blockIdx.z;
    int tid = threadIdx.x;
    int r = tid >> 2, c0 = (tid & 3) * 16;
    size_t so = ((size_t)(b * 256 + ct * 64 + r)) * 1024 + lt * 64 + c0;
    const float* src = x + so;
    ushort* db = xb + so;
#pragma unroll
    for (int i = 0; i < 16; i += 4) {
        float4 v = *(const float4*)(src + i);
        ushort4 u = { f2bf(v.x), f2bf(v.y), f2bf(v.z), f2bf(v.w) };
        *(ushort4*)(db + i) = u;
        *(ushort4*)(&t[r][c0 + i]) = u;
    }
    __syncthreads();
    ushort* dl = xlc + ((size_t)(b * 1024 + lt * 64 + r)) * 256 + ct * 64 + c0;
#pragma unroll
    for (int i = 0; i < 16; i += 4) {
        ushort4 u = { t[c0 + i][r], t[c0 + i + 1][r], t[c0 + i + 2][r], t[c0 + i + 3][r] };
        *(ushort4*)(dl + i) = u;
    }
}

// ---------------- W[h][d][c] fp32 -> WT[h][c][d] bf16 (3 weights via blockIdx.z)
__global__ __launch_bounds__(256) void wprep(const float* __restrict__ Wq, const float* __restrict__ Wk,
                                             const float* __restrict__ Wv,
                                             ushort* __restrict__ WqT, ushort* __restrict__ WkT,
                                             ushort* __restrict__ WvT) {
    __shared__ __align__(16) ushort t[64][72];
    int which = blockIdx.z;
    const float* src = which == 0 ? Wq : which == 1 ? Wk : Wv;
    ushort* dst = which == 0 ? WqT : which == 1 ? WkT : WvT;
    int h = blockIdx.y;
    int tr = blockIdx.x >> 2, tc = blockIdx.x & 3;
    int tid = threadIdx.x;
    int r = tid >> 2, c0 = (tid & 3) * 16;
    const float* s = src + (size_t)h * 65536 + (size_t)(tr * 64 + r) * 256 + tc * 64 + c0;
#pragma unroll
    for (int i = 0; i < 16; i += 4) {
        float4 v = *(const float4*)(s + i);
        ushort4 u = { f2bf(v.x), f2bf(v.y), f2bf(v.z), f2bf(v.w) };
        *(ushort4*)(&t[r][c0 + i]) = u;
    }
    __syncthreads();
    ushort* d = dst + (size_t)h * 65536 + (size_t)(tc * 64 + r) * 256 + tr * 64 + c0;
#pragma unroll
    for (int i = 0; i < 16; i += 4) {
        ushort4 u = { t[c0 + i][r], t[c0 + i + 1][r], t[c0 + i + 2][r], t[c0 + i + 3][r] };
        *(ushort4*)(d + i) = u;
    }
}

// ---------------- Wo [256][1024] fp32 -> bf16
__global__ __launch_bounds__(256) void wocvt(const float* __restrict__ Wo, ushort* __restrict__ o) {
    int i = (blockIdx.x * 256 + threadIdx.x) * 4;
    float4 v = *(const float4*)(Wo + i);
    ushort4 u = { f2bf(v.x), f2bf(v.y), f2bf(v.z), f2bf(v.w) };
    *(ushort4*)(o + i) = u;
}

// ---------------- generic D = X @ Y^T, 128x128 tile, 4 waves, bf16 MFMA 16x16x32
// batch z = blockIdx.y; operand offsets = (z&3)*s0 + (z>>2)*s1 (elements)
__global__ __launch_bounds__(256) void gemm_xyt(
    const ushort* __restrict__ X, const ushort* __restrict__ Y, void* __restrict__ Oraw,
    int M, int N, int K, int ldx, int ldy, int ldo,
    long xs0, long xs1, long ys0, long ys1, long os0, long os1,
    const float* __restrict__ bias, int out_bf16) {
    __shared__ __align__(16) ushort lA[128 * 32];
    __shared__ __align__(16) ushort lB[128 * 32];
    int z = blockIdx.y;
    const ushort* Xb = X + (size_t)(z & 3) * xs0 + (size_t)(z >> 2) * xs1;
    const ushort* Yb = Y + (size_t)(z & 3) * ys0 + (size_t)(z >> 2) * ys1;
    size_t ooff = (size_t)(z & 3) * os0 + (size_t)(z >> 2) * os1;

    int ntn = N >> 7;
    int tm = blockIdx.x / ntn, tn = blockIdx.x % ntn;
    int row0 = tm << 7, col0 = tn << 7;

    int tid = threadIdx.x;
    int wave = tid >> 6, lane = tid & 63;
    int wr = wave >> 1, wc = wave & 1;
    int rA = lane & 15, kg = lane >> 4;
    int srow = lane >> 2, scol = (lane & 3) * 8;

    f4v acc[4][4] = {};

    for (int kt = 0; kt < K; kt += 32) {
#pragma unroll
        for (int i = 0; i < 2; ++i) {
            int ch = i * 4 + wave;
            int rr = ch * 16 + srow;
            gload16(Xb + (size_t)(row0 + rr) * ldx + kt + scol, &lA[ch * 512]);
            gload16(Yb + (size_t)(col0 + rr) * ldy + kt + scol, &lB[ch * 512]);
        }
        __syncthreads();
        s8v a[4], bq[4];
#pragma unroll
        for (int m = 0; m < 4; ++m)
            a[m] = *(const s8v*)&lA[(wr * 64 + m * 16 + rA) * 32 + kg * 8];
#pragma unroll
        for (int n = 0; n < 4; ++n)
            bq[n] = *(const s8v*)&lB[(wc * 64 + n * 16 + rA) * 32 + kg * 8];
#pragma unroll
        for (int m = 0; m < 4; ++m)
#pragma unroll
            for (int n = 0; n < 4; ++n)
                acc[m][n] = __builtin_amdgcn_mfma_f32_16x16x32_bf16(a[m], bq[n], acc[m][n], 0, 0, 0);
        __syncthreads();
    }

    int r4 = (lane >> 4) * 4, cl = lane & 15;
    if (out_bf16) {
        ushort* O = (ushort*)Oraw + ooff;
#pragma unroll
        for (int m = 0; m < 4; ++m)
#pragma unroll
            for (int n = 0; n < 4; ++n) {
                int row = row0 + wr * 64 + m * 16 + r4;
                int col = col0 + wc * 64 + n * 16 + cl;
#pragma unroll
                for (int r = 0; r < 4; ++r)
                    O[(size_t)(row + r) * ldo + col] = f2bf(acc[m][n][r]);
            }
    } else {
        float* O = (float*)Oraw + ooff;
#pragma unroll
        for (int m = 0; m < 4; ++m)
#pragma unroll
            for (int n = 0; n < 4; ++n) {
                int row = row0 + wr * 64 + m * 16 + r4;
                int col = col0 + wc * 64 + n * 16 + cl;
#pragma unroll
                for (int r = 0; r < 4; ++r) {
                    float bv = bias ? bias[row + r] : 0.f;
                    O[(size_t)(row + r) * ldo + col] = acc[m][n][r] + bv;
                }
            }
    }
}

extern "C" void kernel_launch(void* const* d_in, const int* in_sizes, int n_in,
                              void* d_out, int out_size, void* d_ws, size_t ws_size,
                              hipStream_t stream) {
    const float* x  = (const float*)d_in[0];
    const float* Wq = (const float*)d_in[1];
    const float* Wk = (const float*)d_in[2];
    const float* Wv = (const float*)d_in[3];
    const float* Wo = (const float*)d_in[4];
    const float* Wb = (const float*)d_in[5];

    char* ws = (char*)d_ws;
    ushort* xb   = (ushort*)(ws + 0);          // 8 MB; reused as T1flat after S is built
    ushort* xlc  = (ushort*)(ws + 8388608);    // 8 MB
    ushort* wqT  = (ushort*)(ws + 16777216);
    ushort* wkT  = (ushort*)(ws + 17301504);
    ushort* wvT  = (ushort*)(ws + 17825792);
    ushort* wo16 = (ushort*)(ws + 18350080);
    ushort* A16  = (ushort*)(ws + 18874368);
    ushort* BT   = (ushort*)(ws + 19398656);   // [256][1024] = [j][h*256+c']
    ushort* S16  = (ushort*)(ws + 19922944);   // [16][256][256]
    ushort* GT   = (ushort*)(ws + 22020096);   // [16][256][256]
    ushort* T1   = xb;                         // [16][256][1024] = [b][c0][h*256+c']

    hipLaunchKernelGGL(wprep, dim3(16, 4, 3), dim3(256), 0, stream, Wq, Wk, Wv, wqT, wkT, wvT);
    hipLaunchKernelGGL(wocvt, dim3(256), dim3(256), 0, stream, Wo, wo16);
    hipLaunchKernelGGL(xprep, dim3(16, 4, 16), dim3(256), 0, stream, x, xb, xlc);

    // A_h = WqT_h @ WkT_h^T   [256,256,K=256], z=h
    hipLaunchKernelGGL(gemm_xyt, dim3(4, 4), dim3(256), 0, stream,
        wqT, wkT, (void*)A16, 256, 256, 256, 256, 256, 256,
        (long)65536, (long)262144, (long)65536, (long)262144, (long)65536, (long)262144,
        (const float*)nullptr, 1);
    // BT_h = Wo_h @ WvT_h^T  -> BTflat[:, h*256: ]   (ldx/ldo = 1024)
    hipLaunchKernelGGL(gemm_xyt, dim3(4, 4), dim3(256), 0, stream,
        wo16, wvT, (void*)BT, 256, 256, 256, 1024, 256, 1024,
        (long)256, (long)1024, (long)65536, (long)262144, (long)256, (long)1024,
        (const float*)nullptr, 1);
    // S_b = xb16_b @ xb16_b^T  [256,256,K=1024], z=b
    hipLaunchKernelGGL(gemm_xyt, dim3(4, 16), dim3(256), 0, stream,
        xb, xb, (void*)S16, 256, 256, 1024, 1024, 1024, 256,
        (long)262144, (long)1048576, (long)262144, (long)1048576, (long)65536, (long)262144,
        (const float*)nullptr, 1);
    // T1[b,h] = A_h @ S_b^T (S symmetric) -> T1flat[b][:, h*256: ]  z = b*4+h
    hipLaunchKernelGGL(gemm_xyt, dim3(4, 64), dim3(256), 0, stream,
        A16, S16, (void*)T1, 256, 256, 256, 256, 256, 1024,
        (long)65536, (long)0, (long)0, (long)65536, (long)256, (long)262144,
        (const float*)nullptr, 1);
    // GT_b = BTflat @ T1_b^T  [256,256,K=1024], z=b  (X shared across b)
    hipLaunchKernelGGL(gemm_xyt, dim3(4, 16), dim3(256), 0, stream,
        BT, T1, (void*)GT, 256, 256, 1024, 1024, 1024, 256,
        (long)0, (long)0, (long)262144, (long)1048576, (long)65536, (long)262144,
        (const float*)nullptr, 1);
    // OUT_b[c][l] = GT_b @ xlc_b^T + bias[c]   [M=256,N=1024,K=256], fp32 out
    hipLaunchKernelGGL(gemm_xyt, dim3(16, 16), dim3(256), 0, stream,
        GT, xlc, d_out, 256, 1024, 256, 256, 256, 1024,
        (long)65536, (long)262144, (long)262144, (long)1048576, (long)262144, (long)1048576,
        Wb, 0);
}

// Round 2
// 67.900 us; speedup vs baseline: 1.6633x; 1.6633x over previous
//
#include <hip/hip_runtime.h>
#include <hip/hip_bf16.h>

typedef __attribute__((ext_vector_type(8))) short s8v;     // 8 bf16 operand
typedef __attribute__((ext_vector_type(4))) float f4v;     // fp32 accum

__device__ inline ushort f2bf(float f) {
    unsigned u = __builtin_bit_cast(unsigned, f);
    unsigned r = (u + 0x7fffu + ((u >> 16) & 1u)) >> 16;   // RTNE
    return (ushort)r;
}

__device__ inline void gload16(const ushort* g, ushort* l) {
    __builtin_amdgcn_global_load_lds(
        (const __attribute__((address_space(1))) unsigned*)g,
        (__attribute__((address_space(3))) unsigned*)l, 16, 0, 0);
}

// ================= fat prep kernel: xprep (1024 jobs) + wprep (192) + wocvt (64)
__global__ __launch_bounds__(256) void kprep(
    const float* __restrict__ x, const float* __restrict__ Wq, const float* __restrict__ Wk,
    const float* __restrict__ Wv, const float* __restrict__ Wo,
    ushort* __restrict__ xb, ushort* __restrict__ xlc,
    ushort* __restrict__ wqT, ushort* __restrict__ wkT, ushort* __restrict__ wvT,
    ushort* __restrict__ wo16) {
    __shared__ __align__(16) ushort t[64][72];
    int j = blockIdx.x, tid = threadIdx.x;
    int r = tid >> 2, c0 = (tid & 3) * 16;
    if (j < 1024) {
        // x [16][256][1024] fp32 -> xb bf16 (straight) + xlc [16][1024][256] bf16 (transposed)
        int lt = j & 15, ct = (j >> 4) & 3, b = j >> 6;
        size_t so = ((size_t)(b * 256 + ct * 64 + r)) * 1024 + lt * 64 + c0;
        const float* src = x + so;
        ushort* db = xb + so;
#pragma unroll
        for (int i = 0; i < 16; i += 4) {
            float4 v = *(const float4*)(src + i);
            ushort4 u = { f2bf(v.x), f2bf(v.y), f2bf(v.z), f2bf(v.w) };
            *(ushort4*)(db + i) = u;
            *(ushort4*)(&t[r][c0 + i]) = u;
        }
        __syncthreads();
        ushort* dl = xlc + ((size_t)(b * 1024 + lt * 64 + r)) * 256 + ct * 64 + c0;
#pragma unroll
        for (int i = 0; i < 16; i += 4) {
            ushort4 u = { t[c0 + i][r], t[c0 + i + 1][r], t[c0 + i + 2][r], t[c0 + i + 3][r] };
            *(ushort4*)(dl + i) = u;
        }
    } else if (j < 1216) {
        // W[h][d][c] fp32 -> WT[h][c][d] bf16
        int q = j - 1024;
        int tile = q & 15, h = (q >> 4) & 3, which = q >> 6;
        const float* src = which == 0 ? Wq : which == 1 ? Wk : Wv;
        ushort* dst = which == 0 ? wqT : which == 1 ? wkT : wvT;
        int tr = tile >> 2, tc = tile & 3;
        const float* s = src + (size_t)h * 65536 + (size_t)(tr * 64 + r) * 256 + tc * 64 + c0;
#pragma unroll
        for (int i = 0; i < 16; i += 4) {
            float4 v = *(const float4*)(s + i);
            ushort4 u = { f2bf(v.x), f2bf(v.y), f2bf(v.z), f2bf(v.w) };
            *(ushort4*)(&t[r][c0 + i]) = u;
        }
        __syncthreads();
        ushort* d = dst + (size_t)h * 65536 + (size_t)(tc * 64 + r) * 256 + tr * 64 + c0;
#pragma unroll
        for (int i = 0; i < 16; i += 4) {
            ushort4 u = { t[c0 + i][r], t[c0 + i + 1][r], t[c0 + i + 2][r], t[c0 + i + 3][r] };
            *(ushort4*)(d + i) = u;
        }
    } else {
        // Wo [256][1024] fp32 -> bf16; 64 jobs x 4096 floats
        int q = j - 1216;
#pragma unroll
        for (int rr = 0; rr < 4; ++rr) {
            int i = (q * 1024 + rr * 256 + tid) * 4;
            float4 v = *(const float4*)(Wo + i);
            ushort4 u = { f2bf(v.x), f2bf(v.y), f2bf(v.z), f2bf(v.w) };
            *(ushort4*)(wo16 + i) = u;
        }
    }
}

// ================= 128x128 tile GEMM: D = X @ Y^T (both K-contiguous), 4 waves
template<int OBF>
__device__ __forceinline__ void gemm128(
    const ushort* __restrict__ Xb, const ushort* __restrict__ Yb,
    int ldx, int ldy, ushort* lA, ushort* lB, int row0, int col0, int K,
    void* __restrict__ Oraw, int ldo, const float* __restrict__ bias) {
    int tid = threadIdx.x;
    int wave = tid >> 6, lane = tid & 63;
    int wr = wave >> 1, wc = wave & 1;
    int rA = lane & 15, kg = lane >> 4;
    int srow = lane >> 2, scol = (lane & 3) * 8;

    f4v acc[4][4] = {};
    for (int kt = 0; kt < K; kt += 32) {
#pragma unroll
        for (int i = 0; i < 2; ++i) {
            int ch = i * 4 + wave;
            int rr = ch * 16 + srow;
            gload16(Xb + (size_t)(row0 + rr) * ldx + kt + scol, &lA[ch * 512]);
            gload16(Yb + (size_t)(col0 + rr) * ldy + kt + scol, &lB[ch * 512]);
        }
        __syncthreads();
        s8v a[4], bq[4];
#pragma unroll
        for (int m = 0; m < 4; ++m)
            a[m] = *(const s8v*)&lA[(wr * 64 + m * 16 + rA) * 32 + kg * 8];
#pragma unroll
        for (int n = 0; n < 4; ++n)
            bq[n] = *(const s8v*)&lB[(wc * 64 + n * 16 + rA) * 32 + kg * 8];
#pragma unroll
        for (int m = 0; m < 4; ++m)
#pragma unroll
            for (int n = 0; n < 4; ++n)
                acc[m][n] = __builtin_amdgcn_mfma_f32_16x16x32_bf16(a[m], bq[n], acc[m][n], 0, 0, 0);
        __syncthreads();
    }

    int r4 = (lane >> 4) * 4, cl = lane & 15;
    if (OBF) {
        ushort* O = (ushort*)Oraw;
#pragma unroll
        for (int m = 0; m < 4; ++m)
#pragma unroll
            for (int n = 0; n < 4; ++n) {
                int row = row0 + wr * 64 + m * 16 + r4;
                int col = col0 + wc * 64 + n * 16 + cl;
#pragma unroll
                for (int r = 0; r < 4; ++r)
                    O[(size_t)(row + r) * ldo + col] = f2bf(acc[m][n][r]);
            }
    } else {
        float* O = (float*)Oraw;
#pragma unroll
        for (int m = 0; m < 4; ++m)
#pragma unroll
            for (int n = 0; n < 4; ++n) {
                int row = row0 + wr * 64 + m * 16 + r4;
                int col = col0 + wc * 64 + n * 16 + cl;
#pragma unroll
                for (int r = 0; r < 4; ++r) {
                    float bv = bias ? bias[row + r] : 0.f;
                    O[(size_t)(row + r) * ldo + col] = acc[m][n][r] + bv;
                }
            }
    }
}

// ================= 64x64 tile GEMM: D = X @ Y^T, 4 waves as 2x2 of 32x32
template<int OBF>
__device__ __forceinline__ void gemm64(
    const ushort* __restrict__ Xb, const ushort* __restrict__ Yb,
    int ldx, int ldy, ushort* lA, ushort* lB, int row0, int col0, int K,
    void* __restrict__ Oraw, int ldo) {
    int tid = threadIdx.x;
    int wave = tid >> 6, lane = tid & 63;
    int wr = wave >> 1, wc = wave & 1;
    int rA = lane & 15, kg = lane >> 4;
    int srow = wave * 16 + (lane >> 2), scol = (lane & 3) * 8;

    f4v acc[2][2] = {};
    for (int kt = 0; kt < K; kt += 32) {
        gload16(Xb + (size_t)(row0 + srow) * ldx + kt + scol, &lA[wave * 512]);
        gload16(Yb + (size_t)(col0 + srow) * ldy + kt + scol, &lB[wave * 512]);
        __syncthreads();
        s8v a[2], bq[2];
#pragma unroll
        for (int m = 0; m < 2; ++m)
            a[m] = *(const s8v*)&lA[(wr * 32 + m * 16 + rA) * 32 + kg * 8];
#pragma unroll
        for (int n = 0; n < 2; ++n)
            bq[n] = *(const s8v*)&lB[(wc * 32 + n * 16 + rA) * 32 + kg * 8];
#pragma unroll
        for (int m = 0; m < 2; ++m)
#pragma unroll
            for (int n = 0; n < 2; ++n)
                acc[m][n] = __builtin_amdgcn_mfma_f32_16x16x32_bf16(a[m], bq[n], acc[m][n], 0, 0, 0);
        __syncthreads();
    }

    int r4 = (lane >> 4) * 4, cl = lane & 15;
    ushort* O = (ushort*)Oraw;
#pragma unroll
    for (int m = 0; m < 2; ++m)
#pragma unroll
        for (int n = 0; n < 2; ++n) {
            int row = row0 + wr * 32 + m * 16 + r4;
            int col = col0 + wc * 32 + n * 16 + cl;
#pragma unroll
            for (int r = 0; r < 4; ++r)
                O[(size_t)(row + r) * ldo + col] = f2bf(acc[m][n][r]);
        }
}

// ================= k2: S (256 jobs, 64^2, K=1024) + A = WqT@WkT^T (16 jobs, 128^2)
__global__ __launch_bounds__(256) void k2_sa(
    const ushort* __restrict__ xb, const ushort* __restrict__ wqT, const ushort* __restrict__ wkT,
    ushort* __restrict__ S16, ushort* __restrict__ A16) {
    __shared__ __align__(16) ushort lds[8192];
    int j = blockIdx.x;
    if (j < 256) {
        int b = j >> 4, tile = j & 15, tm = tile >> 2, tn = tile & 3;
        const ushort* Xb = xb + (size_t)b * 262144;
        gemm64<1>(Xb, Xb, 1024, 1024, lds, lds + 4096, tm * 64, tn * 64, 1024,
                  S16 + (size_t)b * 65536, 256);
    } else {
        int q = j - 256, h = q >> 2, tm = (q >> 1) & 1, tn = q & 1;
        gemm128<1>(wqT + h * 65536, wkT + h * 65536, 256, 256, lds, lds + 4096,
                   tm * 128, tn * 128, 256, A16 + h * 65536, 256, nullptr);
    }
}

// ================= k3: T1[b][c0][h*256+c'] = A_h @ S_b^T (256 jobs) + BT = Wo_h @ WvT^T (16 jobs)
__global__ __launch_bounds__(256) void k3_t1(
    const ushort* __restrict__ A16, const ushort* __restrict__ S16,
    const ushort* __restrict__ wo16, const ushort* __restrict__ wvT,
    ushort* __restrict__ T1, ushort* __restrict__ BT) {
    __shared__ __align__(16) ushort lds[8192];
    int j = blockIdx.x;
    if (j < 256) {
        int tile = j & 3, z = j >> 2;
        int h = z & 3, b = z >> 2;
        int tm = tile >> 1, tn = tile & 1;
        gemm128<1>(A16 + h * 65536, S16 + (size_t)b * 65536, 256, 256, lds, lds + 4096,
                   tm * 128, tn * 128, 256, T1 + (size_t)b * 262144 + h * 256, 1024, nullptr);
    } else {
        int q = j - 256, h = q >> 2, tm = (q >> 1) & 1, tn = q & 1;
        gemm128<1>(wo16 + h * 256, wvT + h * 65536, 1024, 256, lds, lds + 4096,
                   tm * 128, tn * 128, 256, BT + h * 256, 1024, nullptr);
    }
}

// ================= k4: GT_b = BTflat @ T1_b^T (256 jobs, 64^2, K=1024)
__global__ __launch_bounds__(256) void k4_gt(
    const ushort* __restrict__ BT, const ushort* __restrict__ T1, ushort* __restrict__ GT) {
    __shared__ __align__(16) ushort lds[8192];
    int j = blockIdx.x;
    int b = j >> 4, tile = j & 15, tm = tile >> 2, tn = tile & 3;
    gemm64<1>(BT, T1 + (size_t)b * 262144, 1024, 1024, lds, lds + 4096, tm * 64, tn * 64, 1024,
              GT + (size_t)b * 65536, 256);
}

// ================= k5: OUT_b[c][l] = GT_b @ xlc_b^T + bias[c]  (256 jobs, 128^2, fp32 out)
__global__ __launch_bounds__(256) void k5_out(
    const ushort* __restrict__ GT, const ushort* __restrict__ xlc,
    float* __restrict__ out, const float* __restrict__ bias) {
    __shared__ __align__(16) ushort lds[8192];
    int j = blockIdx.x;
    int b = j >> 4, tile = j & 15, tm = tile >> 3, tn = tile & 7;
    gemm128<0>(GT + (size_t)b * 65536, xlc + (size_t)b * 262144, 256, 256, lds, lds + 4096,
               tm * 128, tn * 128, 256, out + (size_t)b * 262144, 1024, bias);
}

extern "C" void kernel_launch(void* const* d_in, const int* in_sizes, int n_in,
                              void* d_out, int out_size, void* d_ws, size_t ws_size,
                              hipStream_t stream) {
    const float* x  = (const float*)d_in[0];
    const float* Wq = (const float*)d_in[1];
    const float* Wk = (const float*)d_in[2];
    const float* Wv = (const float*)d_in[3];
    const float* Wo = (const float*)d_in[4];
    const float* Wb = (const float*)d_in[5];

    char* ws = (char*)d_ws;
    ushort* xb   = (ushort*)(ws + 0);          // 8 MB; reused as T1 after S is consumed... (T1 aliases xb)
    ushort* xlc  = (ushort*)(ws + 8388608);    // 8 MB
    ushort* wqT  = (ushort*)(ws + 16777216);
    ushort* wkT  = (ushort*)(ws + 17301504);
    ushort* wvT  = (ushort*)(ws + 17825792);
    ushort* wo16 = (ushort*)(ws + 18350080);
    ushort* A16  = (ushort*)(ws + 18874368);
    ushort* BT   = (ushort*)(ws + 19398656);   // [256][1024] = [j][h*256+c']
    ushort* S16  = (ushort*)(ws + 19922944);   // [16][256][256]
    ushort* GT   = (ushort*)(ws + 22020096);   // [16][256][256]
    ushort* T1   = xb;                         // [16][256][1024] = [b][c0][h*256+c']

    hipLaunchKernelGGL(kprep, dim3(1280), dim3(256), 0, stream,
                       x, Wq, Wk, Wv, Wo, xb, xlc, wqT, wkT, wvT, wo16);
    hipLaunchKernelGGL(k2_sa, dim3(272), dim3(256), 0, stream, xb, wqT, wkT, S16, A16);
    hipLaunchKernelGGL(k3_t1, dim3(272), dim3(256), 0, stream, A16, S16, wo16, wvT, T1, BT);
    hipLaunchKernelGGL(k4_gt, dim3(256), dim3(256), 0, stream, BT, T1, GT);
    hipLaunchKernelGGL(k5_out, dim3(256), dim3(256), 0, stream, GT, xlc, (float*)d_out, Wb);
}

// Round 3
// 46.572 us; speedup vs baseline: 2.4250x; 1.4580x over previous
//
#include <hip/hip_runtime.h>
#include <hip/hip_bf16.h>

typedef __attribute__((ext_vector_type(8))) short s8v;     // 8 bf16 operand
typedef __attribute__((ext_vector_type(4))) float f4v;     // fp32 accum

__device__ inline ushort f2bf(float f) {
    unsigned u = __builtin_bit_cast(unsigned, f);
    unsigned r = (u + 0x7fffu + ((u >> 16) & 1u)) >> 16;   // RTNE
    return (ushort)r;
}

__device__ inline void gload16(const ushort* g, ushort* l) {
    __builtin_amdgcn_global_load_lds(
        (const __attribute__((address_space(1))) unsigned*)g,
        (__attribute__((address_space(3))) unsigned*)l, 16, 0, 0);
}

// ================= fat prep kernel: xprep (1024 jobs) + wprep (192) + wocvt (64)
__global__ __launch_bounds__(256) void kprep(
    const float* __restrict__ x, const float* __restrict__ Wq, const float* __restrict__ Wk,
    const float* __restrict__ Wv, const float* __restrict__ Wo,
    ushort* __restrict__ xb, ushort* __restrict__ xlc,
    ushort* __restrict__ wqT, ushort* __restrict__ wkT, ushort* __restrict__ wvT,
    ushort* __restrict__ wo16) {
    __shared__ __align__(16) ushort t[64][72];
    int j = blockIdx.x, tid = threadIdx.x;
    int r = tid >> 2, c0 = (tid & 3) * 16;
    if (j < 1024) {
        int lt = j & 15, ct = (j >> 4) & 3, b = j >> 6;
        size_t so = ((size_t)(b * 256 + ct * 64 + r)) * 1024 + lt * 64 + c0;
        const float* src = x + so;
        ushort* db = xb + so;
#pragma unroll
        for (int i = 0; i < 16; i += 4) {
            float4 v = *(const float4*)(src + i);
            ushort4 u = { f2bf(v.x), f2bf(v.y), f2bf(v.z), f2bf(v.w) };
            *(ushort4*)(db + i) = u;
            *(ushort4*)(&t[r][c0 + i]) = u;
        }
        __syncthreads();
        ushort* dl = xlc + ((size_t)(b * 1024 + lt * 64 + r)) * 256 + ct * 64 + c0;
#pragma unroll
        for (int i = 0; i < 16; i += 4) {
            ushort4 u = { t[c0 + i][r], t[c0 + i + 1][r], t[c0 + i + 2][r], t[c0 + i + 3][r] };
            *(ushort4*)(dl + i) = u;
        }
    } else if (j < 1216) {
        int q = j - 1024;
        int tile = q & 15, h = (q >> 4) & 3, which = q >> 6;
        const float* src = which == 0 ? Wq : which == 1 ? Wk : Wv;
        ushort* dst = which == 0 ? wqT : which == 1 ? wkT : wvT;
        int tr = tile >> 2, tc = tile & 3;
        const float* s = src + (size_t)h * 65536 + (size_t)(tr * 64 + r) * 256 + tc * 64 + c0;
#pragma unroll
        for (int i = 0; i < 16; i += 4) {
            float4 v = *(const float4*)(s + i);
            ushort4 u = { f2bf(v.x), f2bf(v.y), f2bf(v.z), f2bf(v.w) };
            *(ushort4*)(&t[r][c0 + i]) = u;
        }
        __syncthreads();
        ushort* d = dst + (size_t)h * 65536 + (size_t)(tc * 64 + r) * 256 + tr * 64 + c0;
#pragma unroll
        for (int i = 0; i < 16; i += 4) {
            ushort4 u = { t[c0 + i][r], t[c0 + i + 1][r], t[c0 + i + 2][r], t[c0 + i + 3][r] };
            *(ushort4*)(d + i) = u;
        }
    } else {
        int q = j - 1216;
#pragma unroll
        for (int rr = 0; rr < 4; ++rr) {
            int i = (q * 1024 + rr * 256 + tid) * 4;
            float4 v = *(const float4*)(Wo + i);
            ushort4 u = { f2bf(v.x), f2bf(v.y), f2bf(v.z), f2bf(v.w) };
            *(ushort4*)(wo16 + i) = u;
        }
    }
}

// LDS fragment-read swizzle: 16B slot index ^= (row>>1)&3.  Write side is
// gload_lds (linear dest), so the SOURCE k-offset is pre-swizzled per-lane:
// scol = ((lane&3) ^ ((lane>>3)&3)) * 8   (staged row = base + lane>>2).

// ================= pipelined 64x64 GEMM: D = X @ Y^T, 4 waves (2x2 of 32x32)
// 4 LDS slots, depth-2 prefetch, counted vmcnt, one s_barrier per k-step.
__device__ __forceinline__ void gemm64p(
    const ushort* __restrict__ Xb, const ushort* __restrict__ Yb,
    int ldx, int ldy, ushort* lds, int row0, int col0, int K,
    ushort* __restrict__ O, int ldo) {
    const int tid = threadIdx.x, wave = tid >> 6, lane = tid & 63;
    const int wr = wave >> 1, wc = wave & 1;
    const int rA = lane & 15, kg = lane >> 4;
    const int srow = wave * 16 + (lane >> 2);
    const int scol = ((lane & 3) ^ ((lane >> 3) & 3)) * 8;
    ushort* LA = lds;            // 4 slots x 2048 ushorts (4KB)
    ushort* LB = lds + 8192;
    const int NT = K >> 5;
    f4v acc[2][2] = {};

    const ushort* gx = Xb + (size_t)(row0 + srow) * ldx + scol;
    const ushort* gy = Yb + (size_t)(col0 + srow) * ldy + scol;
    gload16(gx + 0,  LA + 0 * 2048 + wave * 512);
    gload16(gy + 0,  LB + 0 * 2048 + wave * 512);
    gload16(gx + 32, LA + 1 * 2048 + wave * 512);
    gload16(gy + 32, LB + 1 * 2048 + wave * 512);

    for (int t = 0; t < NT; ++t) {
        if (t + 2 < NT) {
            int s2 = (t + 2) & 3, kt = (t + 2) << 5;
            gload16(gx + kt, LA + s2 * 2048 + wave * 512);
            gload16(gy + kt, LB + s2 * 2048 + wave * 512);
            asm volatile("s_waitcnt vmcnt(4)" ::: "memory");
        } else if (t + 1 < NT) {
            asm volatile("s_waitcnt vmcnt(2)" ::: "memory");
        } else {
            asm volatile("s_waitcnt vmcnt(0)" ::: "memory");
        }
        __builtin_amdgcn_s_barrier();
        __builtin_amdgcn_sched_barrier(0);
        const int s = t & 3;
        const ushort* pa = LA + s * 2048;
        const ushort* pb = LB + s * 2048;
        s8v a[2], b[2];
#pragma unroll
        for (int m = 0; m < 2; ++m) {
            int row = wr * 32 + m * 16 + rA;
            a[m] = *(const s8v*)&pa[row * 32 + ((kg ^ ((row >> 1) & 3)) << 3)];
        }
#pragma unroll
        for (int n = 0; n < 2; ++n) {
            int row = wc * 32 + n * 16 + rA;
            b[n] = *(const s8v*)&pb[row * 32 + ((kg ^ ((row >> 1) & 3)) << 3)];
        }
#pragma unroll
        for (int m = 0; m < 2; ++m)
#pragma unroll
            for (int n = 0; n < 2; ++n)
                acc[m][n] = __builtin_amdgcn_mfma_f32_16x16x32_bf16(a[m], b[n], acc[m][n], 0, 0, 0);
    }

    int r4 = (lane >> 4) * 4, cl = lane & 15;
#pragma unroll
    for (int m = 0; m < 2; ++m)
#pragma unroll
        for (int n = 0; n < 2; ++n) {
            int row = row0 + wr * 32 + m * 16 + r4;
            int col = col0 + wc * 32 + n * 16 + cl;
#pragma unroll
            for (int r = 0; r < 4; ++r)
                O[(size_t)(row + r) * ldo + col] = f2bf(acc[m][n][r]);
        }
}

// ================= pipelined 128x128 GEMM: D = X @ Y^T, 4 waves (2x2 of 64x64)
template<int OBF>
__device__ __forceinline__ void gemm128p(
    const ushort* __restrict__ Xb, const ushort* __restrict__ Yb,
    int ldx, int ldy, ushort* lds, int row0, int col0, int K,
    void* __restrict__ Oraw, int ldo, const float* __restrict__ bias) {
    const int tid = threadIdx.x, wave = tid >> 6, lane = tid & 63;
    const int wr = wave >> 1, wc = wave & 1;
    const int rA = lane & 15, kg = lane >> 4;
    const int sr = lane >> 2;
    const int scol = ((lane & 3) ^ ((lane >> 3) & 3)) * 8;
    ushort* LA = lds;             // 4 slots x 4096 ushorts (8KB)
    ushort* LB = lds + 16384;
    const int NT = K >> 5;
    f4v acc[4][4] = {};

    const int ch0 = wave, ch1 = 4 + wave;
    const ushort* gx0 = Xb + (size_t)(row0 + ch0 * 16 + sr) * ldx + scol;
    const ushort* gx1 = Xb + (size_t)(row0 + ch1 * 16 + sr) * ldx + scol;
    const ushort* gy0 = Yb + (size_t)(col0 + ch0 * 16 + sr) * ldy + scol;
    const ushort* gy1 = Yb + (size_t)(col0 + ch1 * 16 + sr) * ldy + scol;

#pragma unroll
    for (int p = 0; p < 2; ++p) {
        int kt = p << 5;
        gload16(gx0 + kt, LA + p * 4096 + ch0 * 512);
        gload16(gx1 + kt, LA + p * 4096 + ch1 * 512);
        gload16(gy0 + kt, LB + p * 4096 + ch0 * 512);
        gload16(gy1 + kt, LB + p * 4096 + ch1 * 512);
    }

    for (int t = 0; t < NT; ++t) {
        if (t + 2 < NT) {
            int s2 = (t + 2) & 3, kt = (t + 2) << 5;
            gload16(gx0 + kt, LA + s2 * 4096 + ch0 * 512);
            gload16(gx1 + kt, LA + s2 * 4096 + ch1 * 512);
            gload16(gy0 + kt, LB + s2 * 4096 + ch0 * 512);
            gload16(gy1 + kt, LB + s2 * 4096 + ch1 * 512);
            asm volatile("s_waitcnt vmcnt(8)" ::: "memory");
        } else if (t + 1 < NT) {
            asm volatile("s_waitcnt vmcnt(4)" ::: "memory");
        } else {
            asm volatile("s_waitcnt vmcnt(0)" ::: "memory");
        }
        __builtin_amdgcn_s_barrier();
        __builtin_amdgcn_sched_barrier(0);
        const int s = t & 3;
        const ushort* pa = LA + s * 4096;
        const ushort* pb = LB + s * 4096;
        s8v a[4], b[4];
#pragma unroll
        for (int m = 0; m < 4; ++m) {
            int row = wr * 64 + m * 16 + rA;
            a[m] = *(const s8v*)&pa[row * 32 + ((kg ^ ((row >> 1) & 3)) << 3)];
        }
#pragma unroll
        for (int n = 0; n < 4; ++n) {
            int row = wc * 64 + n * 16 + rA;
            b[n] = *(const s8v*)&pb[row * 32 + ((kg ^ ((row >> 1) & 3)) << 3)];
        }
#pragma unroll
        for (int m = 0; m < 4; ++m)
#pragma unroll
            for (int n = 0; n < 4; ++n)
                acc[m][n] = __builtin_amdgcn_mfma_f32_16x16x32_bf16(a[m], b[n], acc[m][n], 0, 0, 0);
    }

    int r4 = (lane >> 4) * 4, cl = lane & 15;
    if (OBF) {
        ushort* O = (ushort*)Oraw;
#pragma unroll
        for (int m = 0; m < 4; ++m)
#pragma unroll
            for (int n = 0; n < 4; ++n) {
                int row = row0 + wr * 64 + m * 16 + r4;
                int col = col0 + wc * 64 + n * 16 + cl;
#pragma unroll
                for (int r = 0; r < 4; ++r)
                    O[(size_t)(row + r) * ldo + col] = f2bf(acc[m][n][r]);
            }
    } else {
        float* O = (float*)Oraw;
#pragma unroll
        for (int m = 0; m < 4; ++m)
#pragma unroll
            for (int n = 0; n < 4; ++n) {
                int row = row0 + wr * 64 + m * 16 + r4;
                int col = col0 + wc * 64 + n * 16 + cl;
#pragma unroll
                for (int r = 0; r < 4; ++r) {
                    float bv = bias ? bias[row + r] : 0.f;
                    O[(size_t)(row + r) * ldo + col] = acc[m][n][r] + bv;
                }
            }
    }
}

// ================= k2: S (256, 64^2, K=1024, XCD-swizzled) + A (16) + BT (16)
__global__ __launch_bounds__(256) void k2_sa(
    const ushort* __restrict__ xb, const ushort* __restrict__ wqT, const ushort* __restrict__ wkT,
    const ushort* __restrict__ wo16, const ushort* __restrict__ wvT,
    ushort* __restrict__ S16, ushort* __restrict__ A16, ushort* __restrict__ BT) {
    __shared__ __align__(16) ushort lds[32768];
    int j = blockIdx.x;
    if (j < 256) {
        int xcd = j & 7, idx = j >> 3;
        int b = 2 * xcd + (idx >> 4), tile = idx & 15;
        int tm = tile >> 2, tn = tile & 3;
        const ushort* Xb = xb + (size_t)b * 262144;
        gemm64p(Xb, Xb, 1024, 1024, lds, tm * 64, tn * 64, 1024,
                S16 + (size_t)b * 65536, 256);
    } else {
        int q = j - 256;
        if (q < 16) {
            int h = q >> 2, tm = (q >> 1) & 1, tn = q & 1;
            gemm128p<1>(wqT + h * 65536, wkT + h * 65536, 256, 256, lds,
                        tm * 128, tn * 128, 256, A16 + h * 65536, 256, nullptr);
        } else {
            q -= 16;
            int h = q >> 2, tm = (q >> 1) & 1, tn = q & 1;
            gemm128p<1>(wo16 + h * 256, wvT + h * 65536, 1024, 256, lds,
                        tm * 128, tn * 128, 256, BT + h * 256, 1024, nullptr);
        }
    }
}

// ================= k3: T1[b][c0][h*256+c'] = A_h @ S_b^T (256, 128^2, K=256)
__global__ __launch_bounds__(256) void k3_t1(
    const ushort* __restrict__ A16, const ushort* __restrict__ S16,
    ushort* __restrict__ T1) {
    __shared__ __align__(16) ushort lds[32768];
    int j = blockIdx.x;
    int xcd = j & 7, idx = j >> 3;
    int b = 2 * xcd + (idx >> 4), h = (idx >> 2) & 3, tile = idx & 3;
    int tm = tile >> 1, tn = tile & 1;
    gemm128p<1>(A16 + h * 65536, S16 + (size_t)b * 65536, 256, 256, lds,
                tm * 128, tn * 128, 256, T1 + (size_t)b * 262144 + h * 256, 1024, nullptr);
}

// ================= k4: GT_b = BTflat @ T1_b^T (256, 64^2, K=1024)
__global__ __launch_bounds__(256) void k4_gt(
    const ushort* __restrict__ BT, const ushort* __restrict__ T1, ushort* __restrict__ GT) {
    __shared__ __align__(16) ushort lds[16384];
    int j = blockIdx.x;
    int xcd = j & 7, idx = j >> 3;
    int b = 2 * xcd + (idx >> 4), tile = idx & 15;
    int tm = tile >> 2, tn = tile & 3;
    gemm64p(BT, T1 + (size_t)b * 262144, 1024, 1024, lds, tm * 64, tn * 64, 1024,
            GT + (size_t)b * 65536, 256);
}

// ================= k5: OUT_b[c][l] = GT_b @ xlc_b^T + bias[c]  (256, 128^2, fp32)
__global__ __launch_bounds__(256) void k5_out(
    const ushort* __restrict__ GT, const ushort* __restrict__ xlc,
    float* __restrict__ out, const float* __restrict__ bias) {
    __shared__ __align__(16) ushort lds[32768];
    int j = blockIdx.x;
    int xcd = j & 7, idx = j >> 3;
    int b = 2 * xcd + (idx >> 4), tile = idx & 15;
    int tm = tile >> 3, tn = tile & 7;
    gemm128p<0>(GT + (size_t)b * 65536, xlc + (size_t)b * 262144, 256, 256, lds,
                tm * 128, tn * 128, 256, out + (size_t)b * 262144, 1024, bias);
}

extern "C" void kernel_launch(void* const* d_in, const int* in_sizes, int n_in,
                              void* d_out, int out_size, void* d_ws, size_t ws_size,
                              hipStream_t stream) {
    const float* x  = (const float*)d_in[0];
    const float* Wq = (const float*)d_in[1];
    const float* Wk = (const float*)d_in[2];
    const float* Wv = (const float*)d_in[3];
    const float* Wo = (const float*)d_in[4];
    const float* Wb = (const float*)d_in[5];

    char* ws = (char*)d_ws;
    ushort* xb   = (ushort*)(ws + 0);          // 8 MB; aliased as T1 after S consumed
    ushort* xlc  = (ushort*)(ws + 8388608);    // 8 MB
    ushort* wqT  = (ushort*)(ws + 16777216);
    ushort* wkT  = (ushort*)(ws + 17301504);
    ushort* wvT  = (ushort*)(ws + 17825792);
    ushort* wo16 = (ushort*)(ws + 18350080);
    ushort* A16  = (ushort*)(ws + 18874368);
    ushort* BT   = (ushort*)(ws + 19398656);   // [256][1024] = [j][h*256+c']
    ushort* S16  = (ushort*)(ws + 19922944);   // [16][256][256]
    ushort* GT   = (ushort*)(ws + 22020096);   // [16][256][256]
    ushort* T1   = xb;                         // [16][256][1024] = [b][c0][h*256+c']

    hipLaunchKernelGGL(kprep, dim3(1280), dim3(256), 0, stream,
                       x, Wq, Wk, Wv, Wo, xb, xlc, wqT, wkT, wvT, wo16);
    hipLaunchKernelGGL(k2_sa, dim3(288), dim3(256), 0, stream,
                       xb, wqT, wkT, wo16, wvT, S16, A16, BT);
    hipLaunchKernelGGL(k3_t1, dim3(256), dim3(256), 0, stream, A16, S16, T1);
    hipLaunchKernelGGL(k4_gt, dim3(256), dim3(256), 0, stream, BT, T1, GT);
    hipLaunchKernelGGL(k5_out, dim3(256), dim3(256), 0, stream, GT, xlc, (float*)d_out, Wb);
}